// Round 13
// baseline (277.499 us; speedup 1.0000x reference)
//
#include <hip/hip_runtime.h>
#include <math.h>

#define NB 8
#define NC 3
#define NH 1024
#define NW 1024
#define EPS 1e-6f

#define BAND 128            // output cols per wave (float2 per lane)
#define CH 32               // output rows per wave
#define KSTEPS (CH + 10)    // 42 product rows per chunk
#define PADW 144            // 8 pad | 128 | 8 pad  (floats)
#define SEGF 256            // floats per ring segment (64 lanes x 16B DMA = 1KB)
// grid: 2048 blocks of 64 threads (1 wave). vs R11: input staging moved from
// VGPR prefetch (compiler pins depth ~1, ~4KB in flight/wave) to a 3-slot LDS
// ring fed by global_load_lds (16B/lane). Counted vmcnt(12) keeps rows k+1,k+2
// (12 DMAs, ~7KB/wave) in flight across every step -> in-flight bytes/CU no
// longer VGPR-bound. Products/h-sum/ring/emit identical to R11 (passed).

typedef __attribute__((address_space(1))) const void gas_t;
typedef __attribute__((address_space(3))) void las_t;

__global__ __launch_bounds__(64, 2)
void lcs_kernel(const float* __restrict__ x, const float* __restrict__ y,
                float* __restrict__ out) {
    __shared__ __align__(16) float R[3][6][SEGF];   // 18 KB input ring
    __shared__ __align__(16) float P[2][3][PADW];   // 3456 B product dbuf

    const int l   = threadIdx.x;                 // 0..63
    const int bid = blockIdx.x;
    const int b     = bid >> 8;
    const int rem   = bid & 255;
    const int band0 = (rem & 7) * BAND;
    const int r0    = (rem >> 3) * CH;

    const size_t chan = (size_t)NH * NW;
    const float* xb = x + (size_t)b * NC * chan;
    const float* yb = y + (size_t)b * NC * chan;

    // ---- DMA source geometry: lane l stages cols band0-8+4l .. +3 ----
    int oc = band0 - 8 + 4 * l;
    oc = oc < 0 ? 0 : (oc > NW - 4 ? NW - 4 : oc);     // clamped, 16B aligned

    // ---- reader masks (identical semantics to R11) ----
    const int gc0 = band0 - 8 + 2 * l;                 // main float2 col (f=2l)
    const int gcE = band0 + 120 + 2 * l;               // extra col (f=128+2l), l<8
    const float mm = (gc0 >= 0) ? 1.f : 0.f;
    const float me = (l < 8 && gcE + 1 <= NW - 1) ? 1.f : 0.f;
    const int eo = 2 * (l & 7);                        // extra read offset (all lanes)

    // 6 DMAs: x/y ch0..2 of row gr -> slot (wave-uniform LDS base + lane*16)
    auto dma_row = [&](int gr, float* slot) {
        const int rc = gr < 0 ? 0 : (gr > NH - 1 ? NH - 1 : gr);
        const size_t ro = (size_t)rc * NW;
        #pragma unroll
        for (int c = 0; c < 3; ++c) {
            const float* gx = xb + c * chan + ro + oc;
            const float* gy = yb + c * chan + ro + oc;
            __builtin_amdgcn_global_load_lds((gas_t*)(const void*)gx,
                                             (las_t*)(void*)(slot + c * SEGF), 16, 0, 0);
            __builtin_amdgcn_global_load_lds((gas_t*)(const void*)gy,
                                             (las_t*)(void*)(slot + (3 + c) * SEGF), 16, 0, 0);
        }
    };

    float* p0 = &R[0][0][0];
    float* p1 = &R[1][0][0];
    float* p2 = &R[2][0][0];
    dma_row(r0 - 5, p0);   // prime rows for k=0, k=1  (12 DMAs outstanding)
    dma_row(r0 - 4, p1);

    float2 ring[3][11];
    #pragma unroll
    for (int p = 0; p < 3; ++p)
        #pragma unroll
        for (int s = 0; s < 11; ++s) ring[p][s] = make_float2(0.f, 0.f);
    float2 vs[3] = {make_float2(0.f,0.f), make_float2(0.f,0.f), make_float2(0.f,0.f)};

    for (int g = 0; g < 4; ++g) {                 // rolled
        const int gg = g & 1;                     // product-LDS parity
        #pragma unroll
        for (int s = 0; s < 11; ++s) {            // unrolled: static ring index
            const int k = g * 11 + s;
            if (k >= KSTEPS) continue;            // uniform

            // ---- stage row k+2 into p2; keep 12 DMAs in flight ----
            if (k + 2 < KSTEPS) {
                dma_row(r0 - 3 + k, p2);
                asm volatile("s_waitcnt vmcnt(12)" ::: "memory");  // row k ready
            } else {
                asm volatile("s_waitcnt vmcnt(0)" ::: "memory");   // tail (2 steps)
            }

            // ---- channel-reduced products of row k (from LDS slot p0) ----
            const int gr = r0 - 5 + k;
            const float rmf = (gr >= 0 && gr < NH) ? 1.f : 0.f;   // scalar
            const float cmM = rmf * mm, cmE = rmf * me;

            float2 pxx = make_float2(0.f,0.f), pyy = pxx, pxy = pxx;
            float2 qxx = pxx, qyy = pxx, qxy = pxx;
            #pragma unroll
            for (int c = 0; c < 3; ++c) {
                const float2 xm = *(const float2*)(p0 + c * SEGF + 2 * l);
                const float2 ym = *(const float2*)(p0 + (3 + c) * SEGF + 2 * l);
                const float2 xe = *(const float2*)(p0 + c * SEGF + 128 + eo);
                const float2 ye = *(const float2*)(p0 + (3 + c) * SEGF + 128 + eo);
                pxx.x += xm.x*xm.x; pxx.y += xm.y*xm.y;
                pyy.x += ym.x*ym.x; pyy.y += ym.y*ym.y;
                pxy.x += xm.x*ym.x; pxy.y += xm.y*ym.y;
                qxx.x += xe.x*xe.x; qxx.y += xe.y*xe.y;
                qyy.x += ye.x*ye.x; qyy.y += ye.y*ye.y;
                qxy.x += xe.x*ye.x; qxy.y += xe.y*ye.y;
            }
            pxx.x *= cmM; pxx.y *= cmM; pyy.x *= cmM; pyy.y *= cmM;
            pxy.x *= cmM; pxy.y *= cmM;
            qxx.x *= cmE; qxx.y *= cmE; qyy.x *= cmE; qyy.y *= cmE;
            qxy.x *= cmE; qxy.y *= cmE;

            // parity-selected product buffer (step s+1 writes the other one)
            const int pp = gg ^ (s & 1);
            float* Pb = &P[pp][0][0];

            ((float2*)(Pb + 0*PADW))[l] = pxx;
            ((float2*)(Pb + 1*PADW))[l] = pyy;
            ((float2*)(Pb + 2*PADW))[l] = pxy;
            if (l < 8) {
                ((float2*)(Pb + 0*PADW))[64 + l] = qxx;
                ((float2*)(Pb + 1*PADW))[64 + l] = qyy;
                ((float2*)(Pb + 2*PADW))[64 + l] = qxy;
            }
            __builtin_amdgcn_wave_barrier();   // REQUIRED: cross-lane RAW fence

            // ---- horizontal 11-tap + vertical running sum (ring) ----
            #pragma unroll
            for (int p = 0; p < 3; ++p) {
                const float* Pq = Pb + p * PADW;
                float2 t[7];
                #pragma unroll
                for (int j = 0; j < 7; ++j)
                    t[j] = *(const float2*)(Pq + 2*l + 2 + 2*j);
                float h0 = ((t[0].y + t[1].x) + (t[1].y + t[2].x))
                         + ((t[2].y + t[3].x) + (t[3].y + t[4].x))
                         + ((t[4].y + t[5].x) + t[5].y);
                float h1 = h0 - t[0].y + t[6].x;
                vs[p].x += h0 - ring[p][s].x;
                vs[p].y += h1 - ring[p][s].y;
                ring[p][s].x = h0;
                ring[p][s].y = h1;
            }

            // ---- emit ----
            if (k >= 10) {
                const int orow = r0 + k - 10;
                const float d0 = __builtin_amdgcn_sqrtf(vs[0].x) *
                                 __builtin_amdgcn_sqrtf(vs[1].x) + EPS;
                const float d1 = __builtin_amdgcn_sqrtf(vs[0].y) *
                                 __builtin_amdgcn_sqrtf(vs[1].y) + EPS;
                float2 o;
                o.x = vs[2].x * __builtin_amdgcn_rcpf(d0);
                o.y = vs[2].y * __builtin_amdgcn_rcpf(d1);
                *(float2*)(out + ((size_t)b * NH + orow) * NW + band0 + 2*l) = o;
            }

            // ---- rotate ring slots (renamed across unrolled copies) ----
            float* tp = p0; p0 = p1; p1 = p2; p2 = tp;
        }
    }
}

extern "C" void kernel_launch(void* const* d_in, const int* in_sizes, int n_in,
                              void* d_out, int out_size, void* d_ws, size_t ws_size,
                              hipStream_t stream) {
    const float* x = (const float*)d_in[0];
    const float* y = (const float*)d_in[1];
    float* out = (float*)d_out;
    lcs_kernel<<<dim3(2048), dim3(64), 0, stream>>>(x, y, out);
}

// Round 19
// 255.453 us; speedup vs baseline: 1.0863x; 1.0863x over previous
//
#include <hip/hip_runtime.h>
#include <math.h>

#define NB 8
#define NC 3
#define NH 1024
#define NW 1024
#define EPS 1e-6f

#define BAND 64             // output cols per wave (32 lanes x float2)
#define CH 32               // output rows per wave
#define KSTEPS (CH + 10)    // 42 product rows per chunk
#define PADW 160            // 80 product cols + tail slack (OOB-lane reads stay in-plane)
// grid: 8 batches * 16 bands * 32 chunks = 4096 blocks of 64 threads (1 wave)
// -> 16 blocks/CU = 4 waves/SIMD (was 2). R13 killed the in-flight-bytes model
// (84KB/CU in flight, rate unchanged); remaining hypothesis: ~500 cyc/step of
// per-wave serial wait that 2 waves/SIMD can't hide. BAND=64 doubles tiles
// with HORIZONTAL (L2-hot, same-row) halo instead of R4's vertical
// (HBM-missing) halo -> physical bytes stay ~245 MB while TLP doubles.

__global__ __launch_bounds__(64, 2)
void lcs_kernel(const float* __restrict__ x, const float* __restrict__ y,
                float* __restrict__ out) {
    __shared__ __align__(16) float P[2][3][PADW];   // parity-buffered products

    const int l   = threadIdx.x;                 // 0..63
    const int bid = blockIdx.x;
    const int b     = bid >> 9;                  // batch
    const int rem   = bid & 511;
    const int band0 = (rem & 15) * BAND;         // 16 bands of 64 cols
    const int r0    = (rem >> 4) * CH;           // 32 chunks of 32 rows

    const size_t chan = (size_t)NH * NW;
    const float* xb = x + (size_t)b * NC * chan;
    const float* yb = y + (size_t)b * NC * chan;

    // lane cursor: product col pair gc0..gc0+1, lanes 0..39 cover the 80-col band
    const int gc0 = band0 - 8 + 2 * l;
    const float cm = (l < 40 && gc0 >= 0 && gc0 + 1 <= NW - 1) ? 1.f : 0.f;
    const int oc = gc0 < 0 ? 0 : (gc0 > NW - 2 ? NW - 2 : gc0);  // clamped, in-row

    float2 cur[6], nxt[6];
    // d[0..2] = x ch0..2, d[3..5] = y ch0..2
    auto ldrow = [&](int gr, float2* d) {
        const int rc = gr < 0 ? 0 : (gr > NH - 1 ? NH - 1 : gr);   // scalar clamp
        const size_t ro = (size_t)rc * NW;
        #pragma unroll
        for (int c = 0; c < 3; ++c) {
            d[c]     = *(const float2*)(xb + c * chan + ro + oc);
            d[3 + c] = *(const float2*)(yb + c * chan + ro + oc);
        }
    };

    ldrow(r0 - 5, cur);   // prime k=0

    float2 ring[3][11];
    #pragma unroll
    for (int p = 0; p < 3; ++p)
        #pragma unroll
        for (int s = 0; s < 11; ++s) ring[p][s] = make_float2(0.f, 0.f);
    float2 vs[3] = {make_float2(0.f,0.f), make_float2(0.f,0.f), make_float2(0.f,0.f)};

    for (int g = 0; g < 4; ++g) {                 // rolled (code stays ~11 steps)
        const int gg = g & 1;                     // k parity = (g&1)^(s&1), 11 odd
        #pragma unroll
        for (int s = 0; s < 11; ++s) {            // unrolled -> static ring index
            const int k = g * 11 + s;
            if (k >= KSTEPS) continue;            // uniform, only g==3,s>=9

            // ---- prefetch next row ----
            if (k + 1 < KSTEPS) ldrow(r0 - 4 + k, nxt);

            // ---- channel-reduced products of current row (lane's col pair) ----
            const int gr = r0 - 5 + k;
            const float rmf = (gr >= 0 && gr < NH) ? 1.f : 0.f;   // scalar
            const float cmr = rmf * cm;

            float2 pxx = make_float2(0.f,0.f), pyy = pxx, pxy = pxx;
            #pragma unroll
            for (int c = 0; c < 3; ++c) {
                const float2 fx = cur[c], fy = cur[3 + c];
                pxx.x += fx.x*fx.x; pxx.y += fx.y*fx.y;
                pyy.x += fy.x*fy.x; pyy.y += fy.y*fy.y;
                pxy.x += fx.x*fy.x; pxy.y += fx.y*fy.y;
            }
            pxx.x *= cmr; pxx.y *= cmr;
            pyy.x *= cmr; pyy.y *= cmr;
            pxy.x *= cmr; pxy.y *= cmr;

            // parity-selected LDS buffer (step s+1 writes the other one)
            const int pp = gg ^ (s & 1);
            float* Pb = &P[pp][0][0];

            if (l < 40) {                          // 40 x f2 = 80 product cols
                *(float2*)(Pb + 0*PADW + 2*l) = pxx;
                *(float2*)(Pb + 1*PADW + 2*l) = pyy;
                *(float2*)(Pb + 2*PADW + 2*l) = pxy;
            }
            __builtin_amdgcn_wave_barrier();   // REQUIRED: cross-lane RAW fence

            // ---- horizontal 11-tap + vertical running sum (ring) ----
            // (lanes >=32 compute garbage from in-plane slack; never emitted)
            #pragma unroll
            for (int p = 0; p < 3; ++p) {
                const float* Pq = Pb + p * PADW;
                float2 t[7];
                #pragma unroll
                for (int j = 0; j < 7; ++j)
                    t[j] = *(const float2*)(Pq + 2*l + 2 + 2*j);
                float h0 = ((t[0].y + t[1].x) + (t[1].y + t[2].x))
                         + ((t[2].y + t[3].x) + (t[3].y + t[4].x))
                         + ((t[4].y + t[5].x) + t[5].y);
                float h1 = h0 - t[0].y + t[6].x;
                vs[p].x += h0 - ring[p][s].x;
                vs[p].y += h1 - ring[p][s].y;
                ring[p][s].x = h0;
                ring[p][s].y = h1;
            }

            // ---- emit (lanes 0..31 own out cols band0+2l..+1) ----
            if (k >= 10 && l < 32) {
                const int orow = r0 + k - 10;
                const float d0 = __builtin_amdgcn_sqrtf(vs[0].x) *
                                 __builtin_amdgcn_sqrtf(vs[1].x) + EPS;
                const float d1 = __builtin_amdgcn_sqrtf(vs[0].y) *
                                 __builtin_amdgcn_sqrtf(vs[1].y) + EPS;
                float2 o;
                o.x = vs[2].x * __builtin_amdgcn_rcpf(d0);
                o.y = vs[2].y * __builtin_amdgcn_rcpf(d1);
                *(float2*)(out + ((size_t)b * NH + orow) * NW + band0 + 2*l) = o;
            }

            // rotate prefetch regs (renamed across unrolled copies)
            if (k + 1 < KSTEPS) {
                #pragma unroll
                for (int i = 0; i < 6; ++i) cur[i] = nxt[i];
            }
        }
    }
}

extern "C" void kernel_launch(void* const* d_in, const int* in_sizes, int n_in,
                              void* d_out, int out_size, void* d_ws, size_t ws_size,
                              hipStream_t stream) {
    const float* x = (const float*)d_in[0];
    const float* y = (const float*)d_in[1];
    float* out = (float*)d_out;
    lcs_kernel<<<dim3(4096), dim3(64), 0, stream>>>(x, y, out);
}